// Round 1
// baseline (466.093 us; speedup 1.0000x reference)
//
#include <hip/hip_runtime.h>
#include <hip/hip_bf16.h>
#include <stdint.h>

// Problem constants
#define H2      1024
#define SEQ     512
#define BATCH   64
#define M_TOTAL (SEQ * BATCH)   // 32768 rows, row m = s*64 + b (enc layout (S,B,H2))

typedef __attribute__((ext_vector_type(8))) short short8;  // 8 bf16 (4 VGPRs)
typedef __attribute__((ext_vector_type(4))) float f32x4;   // mfma acc

// Pack two fp32 -> one uint holding two bf16 (RNE), lo in low 16 bits.
__device__ __forceinline__ unsigned pack2_bf16(float lo, float hi) {
    union { __hip_bfloat162 h; unsigned u; } v;
    v.h = __float22bfloat162_rn(make_float2(lo, hi));
    return v.u;
}

__device__ __forceinline__ float fast_tanh(float x) {
    float e = __expf(2.0f * x);
    return __fdividef(e - 1.0f, e + 1.0f);
}

// ------------------------------------------------------------------
// Kernel 1: convert W1 encoder slice (cols 2048..3071) to bf16, K-major.
// W1e[h][k] = bf16(W1[h][2048+k]), h<1024, k<1024. 262144 tasks x 4 elems.
__global__ __launch_bounds__(256) void k_prep(const float* __restrict__ W1,
                                              unsigned short* __restrict__ W1e) {
    int i = blockIdx.x * 256 + threadIdx.x;     // grid = 1024 blocks -> exactly 262144
    int e = i << 2;
    int h = e >> 10, k = e & 1023;
    float4 v = *(const float4*)(W1 + (size_t)h * 3072 + 2048 + k);
    uint2 o;
    o.x = pack2_bf16(v.x, v.y);
    o.y = pack2_bf16(v.z, v.w);
    *(uint2*)(W1e + ((size_t)h << 10) + k) = o;
}

// ------------------------------------------------------------------
// Kernel 2: state projection sp[b][h] = sum_k st[b,k]*W1[h,k] + b1[h], K=2048.
// st[b, l*1024+j] = state[l, b, j]. MFMA 16x16x32, direct-from-global fragments
// with in-register fp32->bf16. Grid 64 blocks x 4 waves = 64x4 (16x16) tiles.
__global__ __launch_bounds__(256) void k_stateproj(const float* __restrict__ W1,
                                                   const float* __restrict__ state,
                                                   const float* __restrict__ b1,
                                                   float* __restrict__ sp) {
    int lane = threadIdx.x & 63;
    int wave = threadIdx.x >> 6;        // n-tile (b) 0..3
    int mT   = blockIdx.x;              // m-tile (h) 0..63
    int c    = lane & 15;
    int kq   = (lane >> 4) << 3;        // 0,8,16,24
    int h    = mT * 16 + c;
    int b    = wave * 16 + c;
    const float* ap = W1 + (size_t)h * 3072 + kq;   // state slice: k in [0,2048)
    f32x4 acc = {0.f, 0.f, 0.f, 0.f};
    #pragma unroll 4
    for (int k0 = 0; k0 < 2048; k0 += 32) {
        int k = k0 + kq;
        float4 a0 = *(const float4*)(ap + k0);
        float4 a1 = *(const float4*)(ap + k0 + 4);
        int l = k >> 10, j = k & 1023;
        const float* bp = state + (((size_t)l * 64 + b) << 10) + j;
        float4 b0 = *(const float4*)bp;
        float4 b1v = *(const float4*)(bp + 4);
        union { short8 s; uint4 u; } fa, fb;
        fa.u.x = pack2_bf16(a0.x, a0.y); fa.u.y = pack2_bf16(a0.z, a0.w);
        fa.u.z = pack2_bf16(a1.x, a1.y); fa.u.w = pack2_bf16(a1.z, a1.w);
        fb.u.x = pack2_bf16(b0.x, b0.y); fb.u.y = pack2_bf16(b0.z, b0.w);
        fb.u.z = pack2_bf16(b1v.x, b1v.y); fb.u.w = pack2_bf16(b1v.z, b1v.w);
        acc = __builtin_amdgcn_mfma_f32_16x16x32_bf16(fa.s, fb.s, acc, 0, 0, 0);
    }
    // C/D layout: col(n=b) = lane&15, row(m=h) = quad*4 + reg
    int quad = lane >> 4;
    int bcol = wave * 16 + c;
    #pragma unroll
    for (int i = 0; i < 4; ++i) {
        int hh = mT * 16 + quad * 4 + i;
        sp[((size_t)bcol << 10) + hh] = acc[i] + b1[hh];
    }
}

// ------------------------------------------------------------------
// Kernel 3: main GEMM C(32768,1024) = enc(fp32->bf16) @ W1e^T, fused epilogue:
// logit[m] += sum_h tanh(C[m,h] + sp[b,h]) * W2[h]   (b = m & 63)
// Tiles: BM=BN=128, BK=32; 4 waves, each 64x64 (4x4 of 16x16x32 mfma).
#define BM 128
#define BN 128
#define BK 32
#define LDT 40   // LDS row stride (bf16 elems): 80B -> 2-way bank conflict only (free)

__global__ __launch_bounds__(256, 2) void k_energy(const float* __restrict__ enc,
                                                   const unsigned short* __restrict__ W1e,
                                                   const float* __restrict__ sp,
                                                   const float* __restrict__ W2,
                                                   float* __restrict__ logits) {
    __shared__ unsigned short As[BM * LDT];
    __shared__ unsigned short Bs[BN * LDT];
    int bid  = blockIdx.x;
    int nT   = bid & 7;          // 8 n-tiles: consecutive blocks share A slice (L2)
    int mT   = bid >> 3;         // 256 m-tiles
    int tid  = threadIdx.x;
    int lane = tid & 63, wave = tid >> 6;
    int wm   = (wave >> 1) << 6; // wave row offset in tile
    int wn   = (wave & 1) << 6;  // wave col offset
    int m0   = mT * BM, n0 = nT * BN;

    // staging: 2 threads per row, 16 elems each
    int arow = tid >> 1;
    int aseg = (tid & 1) << 4;
    const float*          apg = enc + ((size_t)(m0 + arow) << 10) + aseg;
    const unsigned short* wpg = W1e + ((size_t)(n0 + arow) << 10) + aseg;
    unsigned short* asd = As + arow * LDT + aseg;
    unsigned short* bsd = Bs + arow * LDT + aseg;

    f32x4 acc[4][4];
    #pragma unroll
    for (int mi = 0; mi < 4; ++mi)
        #pragma unroll
        for (int ni = 0; ni < 4; ++ni)
            acc[mi][ni] = (f32x4){0.f, 0.f, 0.f, 0.f};

    int c  = lane & 15;
    int kq = (lane >> 4) << 3;
    const unsigned short* afp = As + (wm + c) * LDT + kq;
    const unsigned short* bfp = Bs + (wn + c) * LDT + kq;

    for (int k0 = 0; k0 < 1024; k0 += BK) {
        float4 a0 = *(const float4*)(apg + k0);
        float4 a1 = *(const float4*)(apg + k0 + 4);
        float4 a2 = *(const float4*)(apg + k0 + 8);
        float4 a3 = *(const float4*)(apg + k0 + 12);
        uint4  w0 = *(const uint4*)(wpg + k0);      // already bf16
        uint4  w1 = *(const uint4*)(wpg + k0 + 8);
        uint4 pa0, pa1;
        pa0.x = pack2_bf16(a0.x, a0.y); pa0.y = pack2_bf16(a0.z, a0.w);
        pa0.z = pack2_bf16(a1.x, a1.y); pa0.w = pack2_bf16(a1.z, a1.w);
        pa1.x = pack2_bf16(a2.x, a2.y); pa1.y = pack2_bf16(a2.z, a2.w);
        pa1.z = pack2_bf16(a3.x, a3.y); pa1.w = pack2_bf16(a3.z, a3.w);
        __syncthreads();                 // previous iter's LDS reads done
        *(uint4*)asd       = pa0;
        *(uint4*)(asd + 8) = pa1;
        *(uint4*)bsd       = w0;
        *(uint4*)(bsd + 8) = w1;
        __syncthreads();                 // stores visible
        short8 af[4], bf[4];
        #pragma unroll
        for (int i = 0; i < 4; ++i) {
            af[i] = *(const short8*)(afp + (i << 4) * LDT);
            bf[i] = *(const short8*)(bfp + (i << 4) * LDT);
        }
        #pragma unroll
        for (int mi = 0; mi < 4; ++mi)
            #pragma unroll
            for (int ni = 0; ni < 4; ++ni)
                acc[mi][ni] = __builtin_amdgcn_mfma_f32_16x16x32_bf16(af[mi], bf[ni], acc[mi][ni], 0, 0, 0);
    }

    // Epilogue: tanh + W2 dot, reduce 16 cols per quad, atomic into logits[b][s]
    int quad = lane >> 4;
    float w2v[4];
    int   hcol[4];
    #pragma unroll
    for (int ni = 0; ni < 4; ++ni) {
        hcol[ni] = n0 + wn + ni * 16 + c;
        w2v[ni]  = W2[hcol[ni]];
    }
    #pragma unroll
    for (int mi = 0; mi < 4; ++mi) {
        #pragma unroll
        for (int i = 0; i < 4; ++i) {
            int m = m0 + wm + mi * 16 + quad * 4 + i;
            int b = m & 63;
            const float* sprow = sp + ((size_t)b << 10);
            float t = 0.f;
            #pragma unroll
            for (int ni = 0; ni < 4; ++ni) {
                float e = acc[mi][ni][i] + sprow[hcol[ni]];
                t = fmaf(fast_tanh(e), w2v[ni], t);
            }
            t += __shfl_xor(t, 1);
            t += __shfl_xor(t, 2);
            t += __shfl_xor(t, 4);
            t += __shfl_xor(t, 8);
            if (c == 0) atomicAdd(logits + (size_t)b * 512 + (m >> 6), t);
        }
    }
}

// ------------------------------------------------------------------
// Kernel 4: softmax over s per b. logits layout [b][s]. alpha -> d_out part 2.
__global__ __launch_bounds__(256) void k_softmax(const float* __restrict__ logits,
                                                 float* __restrict__ alpha) {
    int b = blockIdx.x;
    int tid = threadIdx.x;
    int lane = tid & 63, wave = tid >> 6;
    float v0 = logits[(size_t)b * 512 + tid];
    float v1 = logits[(size_t)b * 512 + 256 + tid];
    float mx = fmaxf(v0, v1);
    #pragma unroll
    for (int o = 32; o; o >>= 1) mx = fmaxf(mx, __shfl_xor(mx, o));
    __shared__ float redm[4];
    if (lane == 0) redm[wave] = mx;
    __syncthreads();
    mx = fmaxf(fmaxf(redm[0], redm[1]), fmaxf(redm[2], redm[3]));
    float e0 = __expf(v0 - mx), e1 = __expf(v1 - mx);
    float s = e0 + e1;
    #pragma unroll
    for (int o = 32; o; o >>= 1) s += __shfl_xor(s, o);
    __shared__ float reds[4];
    if (lane == 0) reds[wave] = s;
    __syncthreads();
    s = reds[0] + reds[1] + reds[2] + reds[3];
    float inv = 1.0f / s;
    alpha[(size_t)b * 512 + tid]       = e0 * inv;
    alpha[(size_t)b * 512 + 256 + tid] = e1 * inv;
}

// ------------------------------------------------------------------
// Kernel 5: context[b][h] = sum_s alpha[b][s] * enc[s][b][h], fp32.
// Grid 512 = 64 b x 8 s-chunks; 256 threads x float4 = full 1024-h row.
__global__ __launch_bounds__(256) void k_context(const float* __restrict__ enc,
                                                 const float* __restrict__ alpha,
                                                 float* __restrict__ ctx) {
    int b  = blockIdx.x & 63;
    int sc = blockIdx.x >> 6;
    int h  = threadIdx.x << 2;
    float4 acc = make_float4(0.f, 0.f, 0.f, 0.f);
    int sbase = sc * 64;
    #pragma unroll 4
    for (int si = 0; si < 64; ++si) {
        int s = sbase + si;
        float a = alpha[(size_t)b * 512 + s];
        float4 e = *(const float4*)(enc + (((size_t)s * 64 + b) << 10) + h);
        acc.x = fmaf(a, e.x, acc.x);
        acc.y = fmaf(a, e.y, acc.y);
        acc.z = fmaf(a, e.z, acc.z);
        acc.w = fmaf(a, e.w, acc.w);
    }
    float* dst = ctx + ((size_t)b << 10) + h;
    atomicAdd(dst + 0, acc.x);
    atomicAdd(dst + 1, acc.y);
    atomicAdd(dst + 2, acc.z);
    atomicAdd(dst + 3, acc.w);
}

// ------------------------------------------------------------------
extern "C" void kernel_launch(void* const* d_in, const int* in_sizes, int n_in,
                              void* d_out, int out_size, void* d_ws, size_t ws_size,
                              hipStream_t stream) {
    const float* state = (const float*)d_in[0];   // (2, 64, 1024)
    const float* enc   = (const float*)d_in[1];   // (512, 64, 1024)
    const float* W1    = (const float*)d_in[2];   // (1024, 3072)
    const float* b1    = (const float*)d_in[3];   // (1024,)
    const float* W2    = (const float*)d_in[4];   // (1, 1024)
    // d_in[5] = b2: dropped — softmax is shift-invariant, context/alpha unchanged.

    float* ctx   = (float*)d_out;                 // (1,64,1024) = 65536 fp32
    float* alpha = (float*)d_out + 65536;         // (64,1,512)  = 32768 fp32

    char* ws = (char*)d_ws;
    unsigned short* W1e    = (unsigned short*)(ws);             // 2 MB bf16 [h][k]
    float*          sp     = (float*)(ws + 2097152);            // 256 KB [b][h]
    float*          logits = (float*)(ws + 2097152 + 262144);   // 128 KB [b][s]

    hipMemsetAsync(logits, 0, 64 * 512 * sizeof(float), stream);
    hipMemsetAsync(ctx, 0, 65536 * sizeof(float), stream);
    k_prep<<<1024, 256, 0, stream>>>(W1, W1e);
    k_stateproj<<<64, 256, 0, stream>>>(W1, state, b1, sp);
    k_energy<<<M_TOTAL / BM * (H2 / BN), 256, 0, stream>>>(enc, W1e, sp, W2, logits);
    k_softmax<<<64, 256, 0, stream>>>(logits, alpha);
    k_context<<<512, 256, 0, stream>>>(enc, alpha, ctx);
}

// Round 2
// 419.622 us; speedup vs baseline: 1.1107x; 1.1107x over previous
//
#include <hip/hip_runtime.h>
#include <hip/hip_bf16.h>
#include <stdint.h>

// Problem constants
#define H2      1024
#define SEQ     512
#define BATCH   64
#define M_TOTAL (SEQ * BATCH)   // 32768 rows, row m = s*64 + b (enc layout (S,B,H2))

typedef __attribute__((ext_vector_type(8))) short short8;  // 8 bf16 (4 VGPRs)
typedef __attribute__((ext_vector_type(4))) float f32x4;   // mfma acc

// Pack two fp32 -> one uint holding two bf16 (RNE), lo in low 16 bits.
__device__ __forceinline__ unsigned pack2_bf16(float lo, float hi) {
    union { __hip_bfloat162 h; unsigned u; } v;
    v.h = __float22bfloat162_rn(make_float2(lo, hi));
    return v.u;
}

__device__ __forceinline__ float fast_tanh(float x) {
    float e = __expf(2.0f * x);
    return __fdividef(e - 1.0f, e + 1.0f);
}

// Async global->LDS, 16B per lane. LDS side is wave-uniform base + lane*16:
// our lane->lds mapping below is exactly lane-contiguous (no padding).
__device__ __forceinline__ void gl_lds16(const unsigned short* g, unsigned short* l) {
    __builtin_amdgcn_global_load_lds(
        (const __attribute__((address_space(1))) unsigned int*)g,
        (__attribute__((address_space(3))) unsigned int*)l, 16, 0, 0);
}

// ------------------------------------------------------------------
// Kernel 1a: convert W1 encoder slice (cols 2048..3071) to bf16, K-major.
__global__ __launch_bounds__(256) void k_prep(const float* __restrict__ W1,
                                              unsigned short* __restrict__ W1e) {
    int i = blockIdx.x * 256 + threadIdx.x;     // 1024 blocks -> 262144 tasks x4
    int e = i << 2;
    int h = e >> 10, k = e & 1023;
    float4 v = *(const float4*)(W1 + (size_t)h * 3072 + 2048 + k);
    uint2 o;
    o.x = pack2_bf16(v.x, v.y);
    o.y = pack2_bf16(v.z, v.w);
    *(uint2*)(W1e + ((size_t)h << 10) + k) = o;
}

// Kernel 1b: convert enc (512,64,1024) fp32 -> bf16, same (m=s*64+b, k) layout.
__global__ __launch_bounds__(256) void k_prep_enc(const float* __restrict__ enc,
                                                  unsigned short* __restrict__ encb) {
    size_t i = ((size_t)blockIdx.x * 256 + threadIdx.x) << 3;  // 8 elems/thread
    float4 v0 = *(const float4*)(enc + i);
    float4 v1 = *(const float4*)(enc + i + 4);
    uint4 o;
    o.x = pack2_bf16(v0.x, v0.y); o.y = pack2_bf16(v0.z, v0.w);
    o.z = pack2_bf16(v1.x, v1.y); o.w = pack2_bf16(v1.z, v1.w);
    *(uint4*)(encb + i) = o;
}

// ------------------------------------------------------------------
// Kernel 2: state projection sp[b][h] = sum_k st[b,k]*W1[h,k] + b1[h], K=2048.
__global__ __launch_bounds__(256) void k_stateproj(const float* __restrict__ W1,
                                                   const float* __restrict__ state,
                                                   const float* __restrict__ b1,
                                                   float* __restrict__ sp) {
    int lane = threadIdx.x & 63;
    int wave = threadIdx.x >> 6;        // n-tile (b) 0..3
    int mT   = blockIdx.x;              // m-tile (h) 0..63
    int c    = lane & 15;
    int kq   = (lane >> 4) << 3;        // 0,8,16,24
    int h    = mT * 16 + c;
    int b    = wave * 16 + c;
    const float* ap = W1 + (size_t)h * 3072 + kq;   // state slice: k in [0,2048)
    f32x4 acc = {0.f, 0.f, 0.f, 0.f};
    #pragma unroll 4
    for (int k0 = 0; k0 < 2048; k0 += 32) {
        int k = k0 + kq;
        float4 a0 = *(const float4*)(ap + k0);
        float4 a1 = *(const float4*)(ap + k0 + 4);
        int l = k >> 10, j = k & 1023;
        const float* bp = state + (((size_t)l * 64 + b) << 10) + j;
        float4 b0 = *(const float4*)bp;
        float4 b1v = *(const float4*)(bp + 4);
        union { short8 s; uint4 u; } fa, fb;
        fa.u.x = pack2_bf16(a0.x, a0.y); fa.u.y = pack2_bf16(a0.z, a0.w);
        fa.u.z = pack2_bf16(a1.x, a1.y); fa.u.w = pack2_bf16(a1.z, a1.w);
        fb.u.x = pack2_bf16(b0.x, b0.y); fb.u.y = pack2_bf16(b0.z, b0.w);
        fb.u.z = pack2_bf16(b1v.x, b1v.y); fb.u.w = pack2_bf16(b1v.z, b1v.w);
        acc = __builtin_amdgcn_mfma_f32_16x16x32_bf16(fa.s, fb.s, acc, 0, 0, 0);
    }
    int quad = lane >> 4;
    int bcol = wave * 16 + c;
    #pragma unroll
    for (int i = 0; i < 4; ++i) {
        int hh = mT * 16 + quad * 4 + i;
        sp[((size_t)bcol << 10) + hh] = acc[i] + b1[hh];
    }
}

// ------------------------------------------------------------------
// Kernel 3: C(32768,1024) = encb @ W1e^T (bf16 MFMA), fused epilogue:
// logit[m] += sum_h tanh(C[m,h] + sp[b,h]) * W2[h],  b = m & 63.
// m97 structure: global_load_lds x16B staging, unpadded LDS, 2-barrier K-loop.
// XCD swizzle: all 8 nT blocks of one mT share bid%8 -> same XCD L2.
#define BM 128
#define BN 128
#define BK 32

__global__ __launch_bounds__(256, 2) void k_energy(const unsigned short* __restrict__ encb,
                                                   const unsigned short* __restrict__ W1e,
                                                   const float* __restrict__ sp,
                                                   const float* __restrict__ W2,
                                                   float* __restrict__ logits) {
    __shared__ unsigned short As[BM * BK];   // 8 KB
    __shared__ unsigned short Bs[BN * BK];   // 8 KB
    int bid = blockIdx.x;
    int c8  = bid & 7;                // XCD id (round-robin dispatch assumption)
    int jj  = bid >> 3;               // 0..255
    int mT  = c8 * 32 + (jj >> 3);    // same-mT blocks share c8 -> same XCD
    int nT  = jj & 7;
    int m0  = mT * BM, n0 = nT * BN;
    int tid  = threadIdx.x;
    int lane = tid & 63, wave = tid >> 6;
    int wm   = (wave >> 1) << 6;
    int wn   = (wave & 1) << 6;

    // staging: each wave covers 32 rows (2 chunks of 16 rows, 1KB each)
    int r    = lane >> 2;             // 0..15 row within chunk
    int kk   = (lane & 3) << 3;       // 0,8,16,24 bf16 col offset
    int srow = wave * 32 + r;
    const unsigned short* gA = encb + (size_t)(m0 + srow) * H2 + kk;
    const unsigned short* gB = W1e  + (size_t)(n0 + srow) * H2 + kk;
    unsigned short* lA = As + srow * BK + kk;
    unsigned short* lB = Bs + srow * BK + kk;

    f32x4 acc[4][4];
    #pragma unroll
    for (int mi = 0; mi < 4; ++mi)
        #pragma unroll
        for (int ni = 0; ni < 4; ++ni)
            acc[mi][ni] = (f32x4){0.f, 0.f, 0.f, 0.f};

    int c  = lane & 15;
    int kq = (lane >> 4) << 3;
    const unsigned short* afp = As + (wm + c) * BK + kq;
    const unsigned short* bfp = Bs + (wn + c) * BK + kq;

    for (int k0 = 0; k0 < H2; k0 += BK) {
        __syncthreads();                       // prev iter's LDS reads retired
        gl_lds16(gA + k0,           lA);
        gl_lds16(gA + 16 * H2 + k0, lA + 16 * BK);
        gl_lds16(gB + k0,           lB);
        gl_lds16(gB + 16 * H2 + k0, lB + 16 * BK);
        __syncthreads();                       // vmcnt(0) drain -> tiles visible
        short8 af[4], bf[4];
        #pragma unroll
        for (int i = 0; i < 4; ++i) {
            af[i] = *(const short8*)(afp + (i << 4) * BK);
            bf[i] = *(const short8*)(bfp + (i << 4) * BK);
        }
        #pragma unroll
        for (int mi = 0; mi < 4; ++mi)
            #pragma unroll
            for (int ni = 0; ni < 4; ++ni)
                acc[mi][ni] = __builtin_amdgcn_mfma_f32_16x16x32_bf16(af[mi], bf[ni], acc[mi][ni], 0, 0, 0);
    }

    // Epilogue: tanh + W2 dot, reduce 16 cols per quad, atomic into logits[b][s]
    int quad = lane >> 4;
    float w2v[4];
    int   hcol[4];
    #pragma unroll
    for (int ni = 0; ni < 4; ++ni) {
        hcol[ni] = n0 + wn + ni * 16 + c;
        w2v[ni]  = W2[hcol[ni]];
    }
    #pragma unroll
    for (int mi = 0; mi < 4; ++mi) {
        #pragma unroll
        for (int i = 0; i < 4; ++i) {
            int m = m0 + wm + mi * 16 + quad * 4 + i;
            int b = m & 63;
            const float* sprow = sp + ((size_t)b << 10);
            float t = 0.f;
            #pragma unroll
            for (int ni = 0; ni < 4; ++ni) {
                float e = acc[mi][ni][i] + sprow[hcol[ni]];
                t = fmaf(fast_tanh(e), w2v[ni], t);
            }
            t += __shfl_xor(t, 1);
            t += __shfl_xor(t, 2);
            t += __shfl_xor(t, 4);
            t += __shfl_xor(t, 8);
            if (c == 0) atomicAdd(logits + (size_t)b * 512 + (m >> 6), t);
        }
    }
}

// Fallback (small ws): fp32 in-loop conversion (round-1 kernel) + XCD swizzle.
#define LDT 40
__global__ __launch_bounds__(256, 2) void k_energy_f32(const float* __restrict__ enc,
                                                       const unsigned short* __restrict__ W1e,
                                                       const float* __restrict__ sp,
                                                       const float* __restrict__ W2,
                                                       float* __restrict__ logits) {
    __shared__ unsigned short As[BM * LDT];
    __shared__ unsigned short Bs[BN * LDT];
    int bid = blockIdx.x;
    int c8  = bid & 7;
    int jj  = bid >> 3;
    int mT  = c8 * 32 + (jj >> 3);
    int nT  = jj & 7;
    int tid  = threadIdx.x;
    int lane = tid & 63, wave = tid >> 6;
    int wm   = (wave >> 1) << 6;
    int wn   = (wave & 1) << 6;
    int m0   = mT * BM, n0 = nT * BN;

    int arow = tid >> 1;
    int aseg = (tid & 1) << 4;
    const float*          apg = enc + ((size_t)(m0 + arow) << 10) + aseg;
    const unsigned short* wpg = W1e + ((size_t)(n0 + arow) << 10) + aseg;
    unsigned short* asd = As + arow * LDT + aseg;
    unsigned short* bsd = Bs + arow * LDT + aseg;

    f32x4 acc[4][4];
    #pragma unroll
    for (int mi = 0; mi < 4; ++mi)
        #pragma unroll
        for (int ni = 0; ni < 4; ++ni)
            acc[mi][ni] = (f32x4){0.f, 0.f, 0.f, 0.f};

    int c  = lane & 15;
    int kq = (lane >> 4) << 3;
    const unsigned short* afp = As + (wm + c) * LDT + kq;
    const unsigned short* bfp = Bs + (wn + c) * LDT + kq;

    for (int k0 = 0; k0 < 1024; k0 += BK) {
        float4 a0 = *(const float4*)(apg + k0);
        float4 a1 = *(const float4*)(apg + k0 + 4);
        float4 a2 = *(const float4*)(apg + k0 + 8);
        float4 a3 = *(const float4*)(apg + k0 + 12);
        uint4  w0 = *(const uint4*)(wpg + k0);
        uint4  w1 = *(const uint4*)(wpg + k0 + 8);
        uint4 pa0, pa1;
        pa0.x = pack2_bf16(a0.x, a0.y); pa0.y = pack2_bf16(a0.z, a0.w);
        pa0.z = pack2_bf16(a1.x, a1.y); pa0.w = pack2_bf16(a1.z, a1.w);
        pa1.x = pack2_bf16(a2.x, a2.y); pa1.y = pack2_bf16(a2.z, a2.w);
        pa1.z = pack2_bf16(a3.x, a3.y); pa1.w = pack2_bf16(a3.z, a3.w);
        __syncthreads();
        *(uint4*)asd       = pa0;
        *(uint4*)(asd + 8) = pa1;
        *(uint4*)bsd       = w0;
        *(uint4*)(bsd + 8) = w1;
        __syncthreads();
        short8 af[4], bf[4];
        #pragma unroll
        for (int i = 0; i < 4; ++i) {
            af[i] = *(const short8*)(afp + (i << 4) * LDT);
            bf[i] = *(const short8*)(bfp + (i << 4) * LDT);
        }
        #pragma unroll
        for (int mi = 0; mi < 4; ++mi)
            #pragma unroll
            for (int ni = 0; ni < 4; ++ni)
                acc[mi][ni] = __builtin_amdgcn_mfma_f32_16x16x32_bf16(af[mi], bf[ni], acc[mi][ni], 0, 0, 0);
    }

    int quad = lane >> 4;
    float w2v[4];
    int   hcol[4];
    #pragma unroll
    for (int ni = 0; ni < 4; ++ni) {
        hcol[ni] = n0 + wn + ni * 16 + c;
        w2v[ni]  = W2[hcol[ni]];
    }
    #pragma unroll
    for (int mi = 0; mi < 4; ++mi) {
        #pragma unroll
        for (int i = 0; i < 4; ++i) {
            int m = m0 + wm + mi * 16 + quad * 4 + i;
            int b = m & 63;
            const float* sprow = sp + ((size_t)b << 10);
            float t = 0.f;
            #pragma unroll
            for (int ni = 0; ni < 4; ++ni) {
                float e = acc[mi][ni][i] + sprow[hcol[ni]];
                t = fmaf(fast_tanh(e), w2v[ni], t);
            }
            t += __shfl_xor(t, 1);
            t += __shfl_xor(t, 2);
            t += __shfl_xor(t, 4);
            t += __shfl_xor(t, 8);
            if (c == 0) atomicAdd(logits + (size_t)b * 512 + (m >> 6), t);
        }
    }
}

// ------------------------------------------------------------------
// Kernel 4: softmax over s per b.
__global__ __launch_bounds__(256) void k_softmax(const float* __restrict__ logits,
                                                 float* __restrict__ alpha) {
    int b = blockIdx.x;
    int tid = threadIdx.x;
    int lane = tid & 63, wave = tid >> 6;
    float v0 = logits[(size_t)b * 512 + tid];
    float v1 = logits[(size_t)b * 512 + 256 + tid];
    float mx = fmaxf(v0, v1);
    #pragma unroll
    for (int o = 32; o; o >>= 1) mx = fmaxf(mx, __shfl_xor(mx, o));
    __shared__ float redm[4];
    if (lane == 0) redm[wave] = mx;
    __syncthreads();
    mx = fmaxf(fmaxf(redm[0], redm[1]), fmaxf(redm[2], redm[3]));
    float e0 = __expf(v0 - mx), e1 = __expf(v1 - mx);
    float s = e0 + e1;
    #pragma unroll
    for (int o = 32; o; o >>= 1) s += __shfl_xor(s, o);
    __shared__ float reds[4];
    if (lane == 0) reds[wave] = s;
    __syncthreads();
    s = reds[0] + reds[1] + reds[2] + reds[3];
    float inv = 1.0f / s;
    alpha[(size_t)b * 512 + tid]       = e0 * inv;
    alpha[(size_t)b * 512 + 256 + tid] = e1 * inv;
}

// ------------------------------------------------------------------
// Kernel 5: context[b][h] = sum_s alpha[b][s] * enc[s][b][h], fp32.
__global__ __launch_bounds__(256) void k_context(const float* __restrict__ enc,
                                                 const float* __restrict__ alpha,
                                                 float* __restrict__ ctx) {
    int b  = blockIdx.x & 63;
    int sc = blockIdx.x >> 6;
    int h  = threadIdx.x << 2;
    float4 acc = make_float4(0.f, 0.f, 0.f, 0.f);
    int sbase = sc * 64;
    #pragma unroll 4
    for (int si = 0; si < 64; ++si) {
        int s = sbase + si;
        float a = alpha[(size_t)b * 512 + s];
        float4 e = *(const float4*)(enc + (((size_t)s * 64 + b) << 10) + h);
        acc.x = fmaf(a, e.x, acc.x);
        acc.y = fmaf(a, e.y, acc.y);
        acc.z = fmaf(a, e.z, acc.z);
        acc.w = fmaf(a, e.w, acc.w);
    }
    float* dst = ctx + ((size_t)b << 10) + h;
    atomicAdd(dst + 0, acc.x);
    atomicAdd(dst + 1, acc.y);
    atomicAdd(dst + 2, acc.z);
    atomicAdd(dst + 3, acc.w);
}

// ------------------------------------------------------------------
extern "C" void kernel_launch(void* const* d_in, const int* in_sizes, int n_in,
                              void* d_out, int out_size, void* d_ws, size_t ws_size,
                              hipStream_t stream) {
    const float* state = (const float*)d_in[0];   // (2, 64, 1024)
    const float* enc   = (const float*)d_in[1];   // (512, 64, 1024)
    const float* W1    = (const float*)d_in[2];   // (1024, 3072)
    const float* b1    = (const float*)d_in[3];   // (1024,)
    const float* W2    = (const float*)d_in[4];   // (1, 1024)
    // d_in[5] = b2: dropped — softmax is shift-invariant.

    float* ctx   = (float*)d_out;                 // (1,64,1024) = 65536 fp32
    float* alpha = (float*)d_out + 65536;         // (64,1,512)  = 32768 fp32

    char* ws = (char*)d_ws;
    unsigned short* W1e    = (unsigned short*)(ws);             // 2 MB bf16 [h][k]
    float*          sp     = (float*)(ws + 2097152);            // 256 KB [b][h]
    float*          logits = (float*)(ws + 2097152 + 262144);   // 128 KB [b][s]
    unsigned short* encb   = (unsigned short*)(ws + 2097152 + 262144 + 131072); // 64 MB

    const size_t need_full = 2097152 + 262144 + 131072 + (size_t)M_TOTAL * H2 * 2;

    hipMemsetAsync(logits, 0, 64 * 512 * sizeof(float), stream);
    hipMemsetAsync(ctx, 0, 65536 * sizeof(float), stream);
    k_prep<<<1024, 256, 0, stream>>>(W1, W1e);
    k_stateproj<<<64, 256, 0, stream>>>(W1, state, b1, sp);
    if (ws_size >= need_full) {
        k_prep_enc<<<16384, 256, 0, stream>>>(enc, encb);
        k_energy<<<M_TOTAL / BM * (H2 / BN), 256, 0, stream>>>(encb, W1e, sp, W2, logits);
    } else {
        k_energy_f32<<<M_TOTAL / BM * (H2 / BN), 256, 0, stream>>>(enc, W1e, sp, W2, logits);
    }
    k_softmax<<<64, 256, 0, stream>>>(logits, alpha);
    k_context<<<512, 256, 0, stream>>>(enc, alpha, ctx);
}